// Round 6
// baseline (213.163 us; speedup 1.0000x reference)
//
#include <hip/hip_runtime.h>
#include <math.h>

// VQ-VAE quantize: z [32,8,16,16] f32, codebook [16384,8] f32
// N=8192 rows, K=16384 codes, D=8.
// Outputs (concatenated f32): z_q [65536], loss [1], idx-as-float [8192].
//
// f[n,k] = 200*dot(z_n,e_k) - 100*||e_k||^2  (= -d/T + row const; softmax &
// argmax shift-invariant). exp underflows for f - m < -87 (matches fp32 ref).
//
// R6 fix of R5's wrong-idx: the argmax test (x==0 at flush) needs the
// recorded f to be BITWISE equal to the reduced max. R4/R5 inlined the
// ||e||^2 computation (plain mul/add) at multiple sites; -ffp-contract=fast
// may contract each site differently -> 1-ulp mismatch -> no x==0 candidate
// -> kmin=INT_MAX for the affected rows. Fixes:
//  (a) bk[k] = -100*||e_k||^2 precomputed ONCE in prep_cb and loaded (as in
//      all passing versions); dot8s is an explicit fmaf chain, so every f
//      recomputation is bitwise identical.
//  (b) safety net: if a row ends with kmin==INT_MAX (or candidate list
//      overflow), take the wave-parallel full-resweep path (~5us) instead
//      of producing garbage. Wave-uniform branch after the reduce.
//
// Perf structure (R4 theory, first time actually measured): ALL 4 waves
// hold the SAME 16 rows in VGPRs (zr[16][8]); each wave sweeps a disjoint
// QUARTER of the codebook for all 16 rows -> 128 FMA per 36 B/lane, each
// code read once per block. Cross-wave max exchange every 1024 codes keeps
// thresholds tight (load-bearing: keeps candidate counts << CAP).
// __launch_bounds__(256,2): ~220 VGPR -> 2 waves/SIMD; one k-iter is
// ~350cy compute vs ~200cy L2 latency with depth-1 ping-pong prefetch.

#define KCODES 16384
#define CAP 192

__device__ __forceinline__ float dot8s(const float (&z)[8], float4 c0,
                                       float4 c1, float b) {
    float a = fmaf(z[0], c0.x, b);
    a = fmaf(z[1], c0.y, a);
    a = fmaf(z[2], c0.z, a);
    a = fmaf(z[3], c0.w, a);
    a = fmaf(z[4], c1.x, a);
    a = fmaf(z[5], c1.y, a);
    a = fmaf(z[6], c1.z, a);
    a = fmaf(z[7], c1.w, a);
    return a;
}

// ---------------- prep: codebook norms + workspace zeroing ----------------
__global__ __launch_bounds__(256) void prep_cb(const float* __restrict__ cb,
                                               float* __restrict__ bk,
                                               float* __restrict__ avgp,
                                               float* __restrict__ scal) {
    int k = blockIdx.x * 256 + threadIdx.x;
    const float4* c4 = (const float4*)cb;
    float4 c0 = c4[2 * k], c1 = c4[2 * k + 1];
    float nrm = c0.x * c0.x + c0.y * c0.y + c0.z * c0.z + c0.w * c0.w
              + c1.x * c1.x + c1.y * c1.y + c1.z * c1.z + c1.w * c1.w;
    bk[k] = -100.0f * nrm;
    avgp[k] = 0.0f;              // ws is poisoned each launch: zero it here
    if (k < 8)    scal[k] = 0.0f;
}

// ---------------- pass 1: 16 shared rows, 4-way K-split sweep ----------------
// Block = 256 thr = 4 waves; block owns rows [16b, 16b+16); wave w sweeps
// codes [4096w, 4096(w+1)) for ALL 16 rows. Grid 512 blocks (= 2/CU exact).
__global__ __launch_bounds__(256, 2) void pass1(
    const float* __restrict__ z, const float* __restrict__ cb,
    const float* __restrict__ bk, float* __restrict__ out_zq,
    float* __restrict__ out_idx, float* __restrict__ scal,
    float* __restrict__ avgp)
{
    __shared__ float wfb[16][CAP];
    __shared__ int   wkb[16][CAP];
    __shared__ int   cnt[16];
    __shared__ float sm[4][16];         // cross-wave max exchange

    const int wave = threadIdx.x >> 6;
    const int lane = threadIdx.x & 63;
    const int row0 = blockIdx.x * 16;
    const int kbase = wave * 4096;      // this wave's quarter of the codebook

    // load 16 rows (block-uniform, L1-hot broadcast), fold the 200x scale in
    float zr[16][8];
#pragma unroll
    for (int r = 0; r < 16; ++r) {
        int row = row0 + r;
        const float* p = z + (row >> 8) * 2048 + (row & 255);
#pragma unroll
        for (int c = 0; c < 8; ++c) zr[r][c] = 200.0f * p[c * 256];
    }
    if (threadIdx.x < 16) cnt[threadIdx.x] = 0;
    __syncthreads();

    const float4* c4 = (const float4*)cb;
    float m[16], mt[16];
#pragma unroll
    for (int r = 0; r < 16; ++r) m[r] = -3.4e38f;

    // intra-wave reduce + cross-wave exchange -> m[] = block-global running max
    auto exchange = [&]() {
#pragma unroll
        for (int off = 32; off; off >>= 1) {
#pragma unroll
            for (int r = 0; r < 16; ++r)
                m[r] = fmaxf(m[r], __shfl_xor(m[r], off));
        }
        if (lane == 0) {
#pragma unroll
            for (int r = 0; r < 16; ++r) sm[wave][r] = m[r];
        }
        __syncthreads();
#pragma unroll
        for (int r = 0; r < 16; ++r)
            m[r] = fmaxf(fmaxf(sm[0][r], sm[1][r]),
                         fmaxf(sm[2][r], sm[3][r]));
        __syncthreads();                 // sm reused next round
#pragma unroll
        for (int r = 0; r < 16; ++r) mt[r] = m[r] - 87.0f;
    };

    // warm-up: first 512 codes of own quarter, max only (threshold priming;
    // these codes are RE-SWEPT below -- coverage must be total)
#pragma unroll 1
    for (int j = 0; j < 8; ++j) {
        int k = kbase + lane + 64 * j;
        float4 c0 = c4[2 * k], c1 = c4[2 * k + 1];
        float b = bk[k];
#pragma unroll
        for (int r = 0; r < 16; ++r)
            m[r] = fmaxf(m[r], dot8s(zr[r], c0, c1, b));
    }
    exchange();

    // ---- main sweep: ALL 64 k-iters of own quarter, ping-pong prefetch ----
    float4 A0, A1, B0, B1; float Ab, Bb;
    auto loadA = [&](int j) { int k = kbase + lane + 64 * j;
                              A0 = c4[2 * k]; A1 = c4[2 * k + 1]; Ab = bk[k]; };
    auto loadB = [&](int j) { int k = kbase + lane + 64 * j;
                              B0 = c4[2 * k]; B1 = c4[2 * k + 1]; Bb = bk[k]; };

    // fast path per k: 128 FMA + 16 cmp; rare work behind __any
    auto comp = [&](int j, float4 c0, float4 c1, float b) {
        const int k = kbase + lane + 64 * j;
        float f[16];
#pragma unroll
        for (int r = 0; r < 16; ++r) f[r] = dot8s(zr[r], c0, c1, b);
        int hit = 0;
#pragma unroll
        for (int r = 0; r < 16; ++r) hit |= (f[r] > mt[r]) ? (1 << r) : 0;
        if (__any(hit)) {                      // wave-uniform, rare
#pragma unroll
            for (int r = 0; r < 16; ++r) {
                if (hit & (1 << r)) {
                    m[r] = fmaxf(m[r], f[r]); mt[r] = m[r] - 87.0f;
                    int s_ = atomicAdd(&cnt[r], 1);
                    if (s_ < CAP) { wfb[r][s_] = f[r]; wkb[r][s_] = k; }
                }
            }
        }
    };

    loadA(0);                                   // prime the pipeline
#pragma unroll 1
    for (int t = 0; t < 4; ++t) {               // 4 chunks of 16 k-iters
#pragma unroll 1
        for (int p = 0; p < 8; ++p) {
            const int j = t * 16 + p * 2;
            loadB(j + 1);
            comp(j, A0, A1, Ab);
            loadA((j + 2) & 63);                // t=3,p=7 wraps (harmless)
            comp(j + 1, B0, B1, Bb);
        }
        exchange();   // after last chunk: m[] = TRUE global row max
    }
    __syncthreads();   // all waves' candidate writes/atomics visible

    // flush: wave w owns rows [4w, 4w+4); candidate lists were appended by
    // all waves (disjoint k ranges -> no duplicate codes per row)
    float entAcc = 0.0f, sqAcc = 0.0f;
#pragma unroll 1
    for (int rr = 0; rr < 4; ++rr) {
        const int r = wave * 4 + rr;
        const int row = row0 + r;
        const float mm = m[r];
        const int c = cnt[r];

        float sl = 0.0f, tl = 0.0f;
        int kmin = 0x7fffffff;
        bool ok = (c <= CAP);

        if (ok) {
            // ---- normal: stats from the recorded candidates ----
            for (int i = lane; i < c; i += 64) {
                float x = wfb[r][i] - mm;    // <= 0; == 0 at the argmax
                float e = 0.0f;
                if (x > -87.0f) {
                    e = __expf(x);
                    sl += e;
                    tl = fmaf(x, e, tl);
                    if (x == 0.0f) kmin = min(kmin, wkb[r][i]);
                }
                wfb[r][i] = e;               // stash e for the avgp loop
            }
#pragma unroll
            for (int off = 32; off; off >>= 1) {
                sl += __shfl_xor(sl, off);
                tl += __shfl_xor(tl, off);
                kmin = min(kmin, __shfl_xor(kmin, off));
            }
            ok = (kmin != 0x7fffffff);       // argmax found? (safety net)
        }

        if (!ok) {
            // ---- overflow / argmax-miss: wave-parallel full resweep ----
            sl = 0.0f; tl = 0.0f; kmin = 0x7fffffff;
            for (int k = lane; k < KCODES; k += 64) {
                float f = dot8s(zr[r], c4[2 * k], c4[2 * k + 1], bk[k]);
                float x = f - mm;
                if (x > -87.0f) {
                    float e = __expf(x);
                    sl += e; tl = fmaf(x, e, tl);
                    if (x == 0.0f) kmin = min(kmin, k);
                }
            }
#pragma unroll
            for (int off = 32; off; off >>= 1) {
                sl += __shfl_xor(sl, off);
                tl += __shfl_xor(tl, off);
                kmin = min(kmin, __shfl_xor(kmin, off));
            }
            float rs = 1.0f / sl;
            for (int k = lane; k < KCODES; k += 64) {
                float f = dot8s(zr[r], c4[2 * k], c4[2 * k + 1], bk[k]);
                float x = f - mm;
                if (x > -87.0f) atomicAdd(&avgp[k], __expf(x) * rs);
            }
        } else {
            float rs = 1.0f / sl;
            for (int i = lane; i < c; i += 64) {
                float e = wfb[r][i];
                if (e != 0.0f) atomicAdd(&avgp[wkb[r][i]], e * rs);
            }
        }

        if (lane == 0) {
            float rs = 1.0f / sl;
            entAcc += tl * rs - logf(sl);
            out_idx[row] = (float)kmin;
            float4 q0 = c4[2 * kmin], q1 = c4[2 * kmin + 1];
            float qv[8] = {q0.x, q0.y, q0.z, q0.w, q1.x, q1.y, q1.z, q1.w};
            int bb = row >> 8, hw = row & 255;
            const float* zraw = z + bb * 2048 + hw;   // raw row (L1-hot)
            float* o = out_zq + bb * 2048 + hw;
#pragma unroll
            for (int ch = 0; ch < 8; ++ch) {
                float raw = zraw[ch * 256];
                o[ch * 256] = qv[ch];
                float dq = qv[ch] - raw;
                sqAcc += dq * dq;
            }
        }
    }
    if (lane == 0) {
        atomicAdd(&scal[0], sqAcc);
        atomicAdd(&scal[1], entAcc);
    }
}

// ---------------- finalize: avg entropy + loss assembly ----------------
__global__ __launch_bounds__(256) void finalize(
    const float* __restrict__ avgp, const float* __restrict__ scal,
    float* __restrict__ out_loss)
{
    float acc = 0.0f;
    for (int k = threadIdx.x; k < KCODES; k += 256) {
        float avg = avgp[k] * (1.0f / 8192.0f);
        acc += avg * logf(avg + 1e-5f);    // avg==0 contributes exactly 0
    }
#pragma unroll
    for (int off = 32; off > 0; off >>= 1) acc += __shfl_xor(acc, off);
    __shared__ float red[4];
    int wave = threadIdx.x >> 6, lane = threadIdx.x & 63;
    if (lane == 0) red[wave] = acc;
    __syncthreads();
    if (threadIdx.x == 0) {
        float T = red[0] + red[1] + red[2] + red[3];   // sum avg*log(avg+eps)
        // loss = 1.25*mean((zq-z)^2) + 0.1*(sample_entropy - avg_entropy)
        float loss = 1.25f * (scal[0] * (1.0f / 65536.0f))
                   + 0.1f * (T - scal[1] * (1.0f / 8192.0f));
        out_loss[0] = loss;
    }
}

extern "C" void kernel_launch(void* const* d_in, const int* in_sizes, int n_in,
                              void* d_out, int out_size, void* d_ws, size_t ws_size,
                              hipStream_t stream) {
    const float* z  = (const float*)d_in[0];   // [32,8,16,16]
    const float* cb = (const float*)d_in[1];   // [16384,8]
    float* out = (float*)d_out;
    float* ws  = (float*)d_ws;

    // workspace layout (floats)
    float* bk   = ws;                // 16384 : -100*||e_k||^2
    float* avgp = ws + 16384;        // 16384 : sum_n p[n,k]
    float* scal = ws + 32768;        // 2     : [sq, entS]  (+6 pad)

    float* out_zq   = out;           // 65536
    float* out_loss = out + 65536;   // 1
    float* out_idx  = out + 65537;   // 8192

    // prep_cb zeroes avgp/scal (ws is re-poisoned every launch)
    prep_cb <<<64,  256, 0, stream>>>(cb, bk, avgp, scal);
    pass1   <<<512, 256, 0, stream>>>(z, cb, bk, out_zq, out_idx, scal, avgp);
    finalize<<<1,   256, 0, stream>>>(avgp, scal, out_loss);
}